// Round 8
// baseline (549.158 us; speedup 1.0000x reference)
//
#include <hip/hip_runtime.h>
#include <hip/hip_bf16.h>

#define NN 30000
#define NE 300000

typedef unsigned short u16;
typedef unsigned int u32;
typedef unsigned long long u64;
typedef short s16x8 __attribute__((ext_vector_type(8)));
typedef float f32x4 __attribute__((ext_vector_type(4)));

__device__ __forceinline__ float bf2f(u16 u) { return __uint_as_float(((u32)u) << 16); }
__device__ __forceinline__ u16 f2bf(float f) {
    u32 u = __float_as_uint(f);
    u32 r = (u + 0x7FFFu + ((u >> 16) & 1u)) >> 16;
    return (u16)r;
}

// ---------------- CSR build ----------------
__global__ void hist_kernel(const int* __restrict__ col, int* __restrict__ deg) {
    int e = blockIdx.x * blockDim.x + threadIdx.x;
    if (e < NE) atomicAdd(&deg[col[e]], 1);
}

__global__ void dis_kernel(const int* __restrict__ deg, float* __restrict__ dis) {
    int i = blockIdx.x * blockDim.x + threadIdx.x;
    if (i < NN) {
        int d = deg[i];
        dis[i] = d > 0 ? rsqrtf((float)d) : 0.0f;
    }
}

__global__ __launch_bounds__(1024) void scan_kernel(const int* __restrict__ deg,
                                                    int* __restrict__ rowptr) {
    __shared__ int buf[1024];
    __shared__ int carry_s;
    if (threadIdx.x == 0) { carry_s = 0; rowptr[0] = 0; }
    __syncthreads();
    for (int base = 0; base < NN; base += 1024) {
        int i = base + (int)threadIdx.x;
        int v = (i < NN) ? deg[i] : 0;
        buf[threadIdx.x] = v;
        __syncthreads();
        for (int off = 1; off < 1024; off <<= 1) {
            int t = (threadIdx.x >= (unsigned)off) ? buf[threadIdx.x - off] : 0;
            __syncthreads();
            buf[threadIdx.x] += t;
            __syncthreads();
        }
        int carry = carry_s;
        if (i < NN) rowptr[i + 1] = carry + buf[threadIdx.x];
        __syncthreads();
        if (threadIdx.x == 1023) carry_s = carry + buf[1023];
        __syncthreads();
    }
}

__global__ void scatter_kernel(const int* __restrict__ row, const int* __restrict__ col,
                               const int* __restrict__ rowptr, int* __restrict__ cursor,
                               const float* __restrict__ dis, int* __restrict__ src,
                               float* __restrict__ ew) {
    int e = blockIdx.x * blockDim.x + threadIdx.x;
    if (e < NE) {
        int c = col[e];
        int r = row[e];
        int pos = rowptr[c] + atomicAdd(&cursor[c], 1);
        src[pos] = r;
        ew[pos] = dis[r] * dis[c];
    }
}

// ---------------- conversions ----------------
__global__ void f2bf_vec(const float* __restrict__ in, u16* __restrict__ out, long n4) {
    long i = (long)blockIdx.x * blockDim.x + threadIdx.x;
    if (i < n4) {
        float4 v = *(const float4*)&in[i * 4];
        u16 o[4] = { f2bf(v.x), f2bf(v.y), f2bf(v.z), f2bf(v.w) };
        *(u64*)&out[i * 4] = *(u64*)o;
    }
}

// transpose + convert: W[k][kk][o] (f32) -> Wt[k][o][kk] (bf16)
__global__ void prep_w(const float* __restrict__ W, u16* __restrict__ Wt, int Kd, int Od) {
    long idx = (long)blockIdx.x * blockDim.x + threadIdx.x;
    long total = 3L * Kd * Od;
    if (idx < total) {
        int kk = idx % Kd;
        long rest = idx / Kd;
        int o = rest % Od;
        int k = rest / Od;
        Wt[idx] = f2bf(W[((long)k * Kd + kk) * Od + o]);
    }
}

// ---------------- pure propagate: out[n] = sum_e norm(e) * h[src(e)] ----------------
template<int U64W>
__global__ __launch_bounds__(U64W < 64 ? 64 : U64W) void prop_node(
    const u16* __restrict__ h, u16* __restrict__ out,
    const int* __restrict__ rowptr, const int* __restrict__ src,
    const float* __restrict__ ew)
{
    int n = blockIdx.x;
    int t = threadIdx.x;
    if (U64W < 64 && t >= U64W) return;
    int beg = rowptr[n], end = rowptr[n + 1];
    const u64* hu = (const u64*)h;
    float a0 = 0.f, a1 = 0.f, a2 = 0.f, a3 = 0.f;
    int e = beg;
    int s = 0; float w = 0.f;
    if (e < end) { s = src[e]; w = ew[e]; }
    while (e < end) {
        int e2 = e + 1; int s2 = 0; float w2 = 0.f;
        if (e2 < end) { s2 = src[e2]; w2 = ew[e2]; }
        u64 v = hu[(size_t)s * U64W + t];
        a0 += w * bf2f((u16)v);
        a1 += w * bf2f((u16)(v >> 16));
        a2 += w * bf2f((u16)(v >> 32));
        a3 += w * bf2f((u16)(v >> 48));
        e = e2; s = s2; w = w2;
    }
    u16 o[4] = { f2bf(a0), f2bf(a1), f2bf(a2), f2bf(a3) };
    ((u64*)out)[(size_t)n * U64W + t] = *(u64*)o;
}

// ---------------- GEMM (BM=128 x BN), 1D grid, yz fastest ----------------
// grid.x = MB * NY * 3; bid%(NY*3) -> (o-block, stack), bid/(NY*3) -> m-block.
template<int BN, int HAS_ADD, int HAS_BIAS, int RELU>
__global__ __launch_bounds__(256) void gemm_one(
    const u16* __restrict__ A, int pitchA, int stOffA,
    const u16* __restrict__ Wt, const float* __restrict__ bias,
    const u16* __restrict__ addend, u16* __restrict__ out,
    int M, int O, int K, int NY)
{
    constexpr int NJ = BN / 32;
    constexpr int NB = (BN * 4) / 256;
    const int nyz = NY * 3;
    const int yz = blockIdx.x % nyz;
    const int mb = blockIdx.x / nyz;
    const int m0 = mb * 128;
    const int o0 = (yz % NY) * BN;
    const int st = yz / NY;
    const u16* Ak = A + (size_t)st * stOffA;
    const u16* Wk = Wt + (size_t)st * O * K;
    __shared__ u16 As[128][40];
    __shared__ u16 Bs[BN][40];
    const int tid = threadIdx.x;
    const int lane = tid & 63, wave = tid >> 6;
    const int wrow = wave >> 1, wcol = wave & 1;
    const int l15 = lane & 15, l4 = lane >> 4;
    f32x4 acc[4][NJ] = {};
    for (int kt = 0; kt < K; kt += 32) {
#pragma unroll
        for (int hh = 0; hh < 2; hh++) {
            int c = tid + hh * 256;
            int row = c >> 2, kc = (c & 3) * 8;
            int gr = m0 + row;
            uint4 v = {0, 0, 0, 0};
            if (gr < M) v = *(const uint4*)&Ak[(size_t)gr * pitchA + kt + kc];
            *(uint4*)&As[row][kc] = v;
        }
#pragma unroll
        for (int hh = 0; hh < NB; hh++) {
            int c = tid + hh * 256;
            int row = c >> 2, kc = (c & 3) * 8;
            *(uint4*)&Bs[row][kc] = *(const uint4*)&Wk[(size_t)(o0 + row) * K + kt + kc];
        }
        __syncthreads();
        s16x8 bfr[NJ];
#pragma unroll
        for (int j = 0; j < NJ; j++)
            bfr[j] = *(const s16x8*)&Bs[wcol * (BN / 2) + j * 16 + l15][l4 * 8];
#pragma unroll
        for (int i = 0; i < 4; i++) {
            s16x8 a = *(const s16x8*)&As[wrow * 64 + i * 16 + l15][l4 * 8];
#pragma unroll
            for (int j = 0; j < NJ; j++)
                acc[i][j] = __builtin_amdgcn_mfma_f32_16x16x32_bf16(a, bfr[j], acc[i][j], 0, 0, 0);
        }
        __syncthreads();
    }
#pragma unroll
    for (int i = 0; i < 4; i++)
#pragma unroll
        for (int j = 0; j < NJ; j++) {
            int cg = o0 + wcol * (BN / 2) + j * 16 + l15;
            float bv = HAS_BIAS ? bias[st * O + cg] : 0.0f;
#pragma unroll
            for (int q = 0; q < 4; q++) {
                int rg = m0 + wrow * 64 + i * 16 + l4 * 4 + q;
                if (rg < M) {
                    float v = acc[i][j][q] + bv;
                    if (HAS_ADD) v += bf2f(addend[((size_t)rg * 3 + st) * O + cg]);
                    if (RELU) v = fmaxf(v, 0.0f);
                    out[((size_t)rg * 3 + st) * O + cg] = f2bf(v);
                }
            }
        }
}

// ---------------- fused dual GEMM (single k-loop, both A tiles in LDS) ----------------
// out1 = A1@W1 + bias (root); out2 = act(A2@W2 + out1). BN=64, 1D grid yz-fastest.
template<int RELU2>
__global__ __launch_bounds__(256) void gemm_dual(
    const u16* __restrict__ A1, const u16* __restrict__ A2,
    const u16* __restrict__ W1, const u16* __restrict__ W2,
    const float* __restrict__ bias,
    u16* __restrict__ out1, u16* __restrict__ out2,
    int M, int O, int K, int NY)
{
    const int nyz = NY * 3;
    const int yz = blockIdx.x % nyz;
    const int mb = blockIdx.x / nyz;
    const int m0 = mb * 128;
    const int o0 = (yz % NY) * 64;
    const int st = yz / NY;
    const u16* W1k = W1 + (size_t)st * O * K;
    const u16* W2k = W2 + (size_t)st * O * K;
    __shared__ u16 As1[128][40];
    __shared__ u16 As2[128][40];
    __shared__ u16 Bs1[64][40];
    __shared__ u16 Bs2[64][40];
    const int tid = threadIdx.x;
    const int lane = tid & 63, wave = tid >> 6;
    const int wrow = wave >> 1, wcol = wave & 1;
    const int l15 = lane & 15, l4 = lane >> 4;
    const int srow = tid >> 2;
    const int skoff = (tid & 3) * 8;

    f32x4 acc1[4][2] = {};
    f32x4 acc2[4][2] = {};
    for (int kt = 0; kt < K; kt += 32) {
#pragma unroll
        for (int hh = 0; hh < 2; hh++) {
            int c = tid + hh * 256;
            int row = c >> 2, kc = (c & 3) * 8;
            int gr = m0 + row;
            uint4 v1 = {0, 0, 0, 0}, v2 = {0, 0, 0, 0};
            if (gr < M) {
                v1 = *(const uint4*)&A1[(size_t)gr * K + kt + kc];
                v2 = *(const uint4*)&A2[(size_t)gr * K + kt + kc];
            }
            *(uint4*)&As1[row][kc] = v1;
            *(uint4*)&As2[row][kc] = v2;
        }
        *(uint4*)&Bs1[srow][skoff] = *(const uint4*)&W1k[(size_t)(o0 + srow) * K + kt + skoff];
        *(uint4*)&Bs2[srow][skoff] = *(const uint4*)&W2k[(size_t)(o0 + srow) * K + kt + skoff];
        __syncthreads();
        s16x8 b10 = *(const s16x8*)&Bs1[wcol * 32 + l15][l4 * 8];
        s16x8 b11 = *(const s16x8*)&Bs1[wcol * 32 + 16 + l15][l4 * 8];
        s16x8 b20 = *(const s16x8*)&Bs2[wcol * 32 + l15][l4 * 8];
        s16x8 b21 = *(const s16x8*)&Bs2[wcol * 32 + 16 + l15][l4 * 8];
#pragma unroll
        for (int i = 0; i < 4; i++) {
            s16x8 a1 = *(const s16x8*)&As1[wrow * 64 + i * 16 + l15][l4 * 8];
            s16x8 a2 = *(const s16x8*)&As2[wrow * 64 + i * 16 + l15][l4 * 8];
            acc1[i][0] = __builtin_amdgcn_mfma_f32_16x16x32_bf16(a1, b10, acc1[i][0], 0, 0, 0);
            acc1[i][1] = __builtin_amdgcn_mfma_f32_16x16x32_bf16(a1, b11, acc1[i][1], 0, 0, 0);
            acc2[i][0] = __builtin_amdgcn_mfma_f32_16x16x32_bf16(a2, b20, acc2[i][0], 0, 0, 0);
            acc2[i][1] = __builtin_amdgcn_mfma_f32_16x16x32_bf16(a2, b21, acc2[i][1], 0, 0, 0);
        }
        __syncthreads();
    }
#pragma unroll
    for (int j = 0; j < 2; j++) {
        int cg = o0 + wcol * 32 + j * 16 + l15;
        float bv = bias[st * O + cg];
#pragma unroll
        for (int i = 0; i < 4; i++)
#pragma unroll
            for (int q = 0; q < 4; q++) {
                int rg = m0 + wrow * 64 + i * 16 + l4 * 4 + q;
                if (rg < M) {
                    float o1 = acc1[i][j][q] + bv;
                    out1[((size_t)rg * 3 + st) * O + cg] = f2bf(o1);
                    float o2 = acc2[i][j][q] + o1;
                    if (RELU2) o2 = fmaxf(o2, 0.0f);
                    out2[((size_t)rg * 3 + st) * O + cg] = f2bf(o2);
                }
            }
    }
}

// ---------------- mean over 3 stacks, F=256: [N][3][256] -> [N][256] ----------------
__global__ void mean3_256(const u16* __restrict__ h, u16* __restrict__ out) {
    long idx = (long)blockIdx.x * blockDim.x + threadIdx.x;  // u32 index
    const long total = (long)NN * 128;
    if (idx >= total) return;
    long n = idx >> 7; int t = (int)(idx & 127);
    const u32* hu = (const u32*)h;
    u32 a = hu[(n * 3 + 0) * 128 + t], b = hu[(n * 3 + 1) * 128 + t], c = hu[(n * 3 + 2) * 128 + t];
    float lo = (bf2f((u16)a) + bf2f((u16)b) + bf2f((u16)c)) * (1.0f / 3.0f);
    float hi = (bf2f((u16)(a >> 16)) + bf2f((u16)(b >> 16)) + bf2f((u16)(c >> 16))) * (1.0f / 3.0f);
    ((u32*)out)[idx] = (u32)f2bf(lo) | ((u32)f2bf(hi) << 16);
}

// ---------------- mean over stacks + log_softmax, g [N][3][64] -> out [N][64] f32 -----
__global__ __launch_bounds__(64) void final_ls(const u16* __restrict__ g, float* __restrict__ out) {
    int n = blockIdx.x;
    int f = threadIdx.x;
    long b0 = (long)n * 192 + f;
    float v = (bf2f(g[b0]) + bf2f(g[b0 + 64]) + bf2f(g[b0 + 128])) * (1.0f / 3.0f);
    float m = v;
    for (int off = 32; off; off >>= 1) m = fmaxf(m, __shfl_xor(m, off, 64));
    float s = expf(v - m);
    for (int off = 32; off; off >>= 1) s += __shfl_xor(s, off, 64);
    out[(long)n * 64 + f] = v - m - logf(s);
}

extern "C" void kernel_launch(void* const* d_in, const int* in_sizes, int n_in,
                              void* d_out, int out_size, void* d_ws, size_t ws_size,
                              hipStream_t stream) {
    const float* x = (const float*)d_in[0];
    const int* ei = (const int*)d_in[1];
    const float* init_w1 = (const float*)d_in[2];
    const float* w1 = (const float*)d_in[3];
    const float* root_w1 = (const float*)d_in[4];
    const float* bias1 = (const float*)d_in[5];
    const float* init_w2 = (const float*)d_in[6];
    const float* w2 = (const float*)d_in[7];
    const float* root_w2 = (const float*)d_in[8];
    const float* bias2 = (const float*)d_in[9];
    float* out = (float*)d_out;
    (void)ws_size; (void)n_in; (void)in_sizes; (void)out_size;

    char* ws = (char*)d_ws;
    size_t off = 0;
    auto alloc = [&](size_t bytes) -> void* {
        void* p = ws + off;
        off += (bytes + 255) & ~(size_t)255;
        return p;
    };
    int* deg = (int*)alloc(NN * 4);
    int* rowptr = (int*)alloc((NN + 1) * 4);
    int* cursor = (int*)alloc(NN * 4);
    int* srcb = (int*)alloc((size_t)NE * 4);
    float* ewb = (float*)alloc((size_t)NE * 4);
    float* dis = (float*)alloc(NN * 4);
    u16* iw1t = (u16*)alloc((size_t)3 * 256 * 256 * 2);
    u16* w1t = (u16*)alloc((size_t)3 * 256 * 256 * 2);
    u16* rw1t = (u16*)alloc((size_t)3 * 256 * 256 * 2);
    u16* iw2t = (u16*)alloc((size_t)3 * 64 * 256 * 2);
    u16* rw2t = (u16*)alloc((size_t)3 * 64 * 256 * 2);
    u16* w2t = (u16*)alloc((size_t)3 * 64 * 64 * 2);
    u16* xb = (u16*)alloc((size_t)NN * 256 * 2);            // x bf16 [N][256]
    u16* bufR = (u16*)alloc((size_t)NN * 3 * 256 * 2);      // root1; then conv2 quads
    u16* bufH = (u16*)alloc((size_t)NN * 3 * 256 * 2);      // h1, then h2
    u16* bufP = (u16*)alloc((size_t)NN * 3 * 256 * 2);      // px | ph1 | hmean
    u16* px = bufP;            // [N][256] (dead before ph1 written)
    u16* hmean = bufP;         // [N][256] (after ph1 dead)
    u16* pm = xb;              // [N][256] (xb dead after dual1)
    // conv2 carves from bufR (root1 dead after h2 GEMM): 4 x 11.52 MB
    u16* root2 = bufR;
    u16* g1 = bufR + (size_t)3 * NN * 64;
    u16* pg1 = bufR + (size_t)6 * NN * 64;
    u16* g2 = bufR + (size_t)9 * NN * 64;

    const int* e_row = ei;
    const int* e_col = ei + NE;

    hipMemsetAsync(deg, 0, NN * 4, stream);
    hipMemsetAsync(cursor, 0, NN * 4, stream);

    hist_kernel<<<(NE + 255) / 256, 256, 0, stream>>>(e_col, deg);
    dis_kernel<<<(NN + 255) / 256, 256, 0, stream>>>(deg, dis);
    scan_kernel<<<1, 1024, 0, stream>>>(deg, rowptr);
    scatter_kernel<<<(NE + 255) / 256, 256, 0, stream>>>(e_row, e_col, rowptr, cursor, dis, srcb, ewb);

    f2bf_vec<<<(NN * 256 / 4 + 255) / 256, 256, 0, stream>>>(x, xb, (long)NN * 256 / 4);
    prep_w<<<(3 * 256 * 256 + 255) / 256, 256, 0, stream>>>(init_w1, iw1t, 256, 256);
    prep_w<<<(3 * 256 * 256 + 255) / 256, 256, 0, stream>>>(w1, w1t, 256, 256);
    prep_w<<<(3 * 256 * 256 + 255) / 256, 256, 0, stream>>>(root_w1, rw1t, 256, 256);
    prep_w<<<(3 * 64 * 256 + 255) / 256, 256, 0, stream>>>(init_w2, iw2t, 256, 64);
    prep_w<<<(3 * 64 * 256 + 255) / 256, 256, 0, stream>>>(root_w2, rw2t, 256, 64);
    prep_w<<<(3 * 64 * 64 + 255) / 256, 256, 0, stream>>>(w2, w2t, 64, 64);

    const int MB = (NN + 127) / 128;  // 235

    // ---- conv1 ----
    // px = prop(x)
    prop_node<64><<<NN, 64, 0, stream>>>(xb, px, rowptr, srcb, ewb);
    // root1 = x@rw1+b1 ; h1 = relu(px@iw1 + root1)   [N][3][256]
    gemm_dual<1><<<MB * 12, 256, 0, stream>>>(xb, px, rw1t, iw1t, bias1,
                                              bufR, bufH, NN, 256, 256, 4);
    // ph1 = prop(h1)  (3-stack, [N][768])
    prop_node<192><<<NN, 192, 0, stream>>>(bufH, bufP, rowptr, srcb, ewb);
    // h2 = relu(ph1@w1 + root1)
    gemm_one<128, 1, 0, 1><<<MB * 6, 256, 0, stream>>>(
        bufP, 768, 256, w1t, nullptr, bufR, bufH, NN, 256, 256, 2);
    // hmean = mean_stacks(h2)   (>=0, so outer relu is a no-op)
    mean3_256<<<(int)(((long)NN * 128 + 255) / 256), 256, 0, stream>>>(bufH, hmean);

    // ---- conv2 ----
    // pm = prop(hmean)
    prop_node<64><<<NN, 64, 0, stream>>>(hmean, pm, rowptr, srcb, ewb);
    // root2 = hmean@rw2+b2 ; g1 = pm@iw2 + root2   [N][3][64]
    gemm_dual<0><<<MB * 3, 256, 0, stream>>>(hmean, pm, rw2t, iw2t, bias2,
                                             root2, g1, NN, 64, 256, 1);
    // pg1 = prop(g1)  (3-stack, [N][192])
    prop_node<48><<<NN, 64, 0, stream>>>(g1, pg1, rowptr, srcb, ewb);
    // g2 = pg1@w2 + root2
    gemm_one<64, 1, 0, 0><<<MB * 3, 256, 0, stream>>>(
        pg1, 192, 64, w2t, nullptr, root2, g2, NN, 64, 64, 1);

    final_ls<<<NN, 64, 0, stream>>>(g2, out);
}

// Round 10
// 505.415 us; speedup vs baseline: 1.0865x; 1.0865x over previous
//
#include <hip/hip_runtime.h>
#include <hip/hip_bf16.h>

#define NN 30000
#define NE 300000

typedef unsigned short u16;
typedef unsigned int u32;
typedef unsigned long long u64;
typedef short s16x8 __attribute__((ext_vector_type(8)));
typedef float f32x4 __attribute__((ext_vector_type(4)));

__device__ __forceinline__ float bf2f(u16 u) { return __uint_as_float(((u32)u) << 16); }
__device__ __forceinline__ u16 f2bf(float f) {
    u32 u = __float_as_uint(f);
    u32 r = (u + 0x7FFFu + ((u >> 16) & 1u)) >> 16;
    return (u16)r;
}

// Bijective XCD swizzle (m204): dispatch round-robins bid%8 across XCDs; remap so
// each XCD owns a CONTIGUOUS wgid range -> A-tiles fetched by exactly one XCD L2.
__device__ __forceinline__ int xcd_map(int bid, int nwg) {
    int xcd = bid & 7;
    int i = bid >> 3;
    int q = nwg >> 3, r = nwg & 7;
    int base = (xcd < r) ? xcd * (q + 1) : r * (q + 1) + (xcd - r) * q;
    return base + i;
}

// ---------------- CSR build ----------------
__global__ void hist_kernel(const int* __restrict__ col, int* __restrict__ deg) {
    int e = blockIdx.x * blockDim.x + threadIdx.x;
    if (e < NE) atomicAdd(&deg[col[e]], 1);
}

__global__ void dis_kernel(const int* __restrict__ deg, float* __restrict__ dis) {
    int i = blockIdx.x * blockDim.x + threadIdx.x;
    if (i < NN) {
        int d = deg[i];
        dis[i] = d > 0 ? rsqrtf((float)d) : 0.0f;
    }
}

__global__ __launch_bounds__(1024) void scan_kernel(const int* __restrict__ deg,
                                                    int* __restrict__ rowptr) {
    __shared__ int buf[1024];
    __shared__ int carry_s;
    if (threadIdx.x == 0) { carry_s = 0; rowptr[0] = 0; }
    __syncthreads();
    for (int base = 0; base < NN; base += 1024) {
        int i = base + (int)threadIdx.x;
        int v = (i < NN) ? deg[i] : 0;
        buf[threadIdx.x] = v;
        __syncthreads();
        for (int off = 1; off < 1024; off <<= 1) {
            int t = (threadIdx.x >= (unsigned)off) ? buf[threadIdx.x - off] : 0;
            __syncthreads();
            buf[threadIdx.x] += t;
            __syncthreads();
        }
        int carry = carry_s;
        if (i < NN) rowptr[i + 1] = carry + buf[threadIdx.x];
        __syncthreads();
        if (threadIdx.x == 1023) carry_s = carry + buf[1023];
        __syncthreads();
    }
}

__global__ void scatter_kernel(const int* __restrict__ row, const int* __restrict__ col,
                               const int* __restrict__ rowptr, int* __restrict__ cursor,
                               const float* __restrict__ dis, int* __restrict__ src,
                               float* __restrict__ ew) {
    int e = blockIdx.x * blockDim.x + threadIdx.x;
    if (e < NE) {
        int c = col[e];
        int r = row[e];
        int pos = rowptr[c] + atomicAdd(&cursor[c], 1);
        src[pos] = r;
        ew[pos] = dis[r] * dis[c];
    }
}

// ---------------- conversions ----------------
__global__ void f2bf_vec(const float* __restrict__ in, u16* __restrict__ out, long n4) {
    long i = (long)blockIdx.x * blockDim.x + threadIdx.x;
    if (i < n4) {
        float4 v = *(const float4*)&in[i * 4];
        u16 o[4] = { f2bf(v.x), f2bf(v.y), f2bf(v.z), f2bf(v.w) };
        *(u64*)&out[i * 4] = *(u64*)o;
    }
}

// transpose + convert: W[k][kk][o] (f32) -> Wt[k][o][kk] (bf16)
__global__ void prep_w(const float* __restrict__ W, u16* __restrict__ Wt, int Kd, int Od) {
    long idx = (long)blockIdx.x * blockDim.x + threadIdx.x;
    long total = 3L * Kd * Od;
    if (idx < total) {
        int kk = idx % Kd;
        long rest = idx / Kd;
        int o = rest % Od;
        int k = rest / Od;
        Wt[idx] = f2bf(W[((long)k * Kd + kk) * Od + o]);
    }
}

// ---------------- pure propagate: out[n] = sum_e norm(e) * h[src(e)] ----------------
template<int U64W>
__global__ __launch_bounds__(U64W < 64 ? 64 : U64W) void prop_node(
    const u16* __restrict__ h, u16* __restrict__ out,
    const int* __restrict__ rowptr, const int* __restrict__ src,
    const float* __restrict__ ew)
{
    int n = blockIdx.x;
    int t = threadIdx.x;
    if (U64W < 64 && t >= U64W) return;
    int beg = rowptr[n], end = rowptr[n + 1];
    const u64* hu = (const u64*)h;
    float a0 = 0.f, a1 = 0.f, a2 = 0.f, a3 = 0.f;
    int e = beg;
    int s = 0; float w = 0.f;
    if (e < end) { s = src[e]; w = ew[e]; }
    while (e < end) {
        int e2 = e + 1; int s2 = 0; float w2 = 0.f;
        if (e2 < end) { s2 = src[e2]; w2 = ew[e2]; }
        u64 v = hu[(size_t)s * U64W + t];
        a0 += w * bf2f((u16)v);
        a1 += w * bf2f((u16)(v >> 16));
        a2 += w * bf2f((u16)(v >> 32));
        a3 += w * bf2f((u16)(v >> 48));
        e = e2; s = s2; w = w2;
    }
    u16 o[4] = { f2bf(a0), f2bf(a1), f2bf(a2), f2bf(a3) };
    ((u64*)out)[(size_t)n * U64W + t] = *(u64*)o;
}

// ---------------- GEMM (BM=128 x BN), 1D grid yz-fastest + XCD swizzle ----------------
// Swapped MFMA operands: lane holds 4 consecutive OUTPUT COLS -> 8B stores.
template<int BN, int HAS_ADD, int HAS_BIAS, int RELU>
__global__ __launch_bounds__(256) void gemm_one(
    const u16* __restrict__ A, int pitchA, int stOffA,
    const u16* __restrict__ Wt, const float* __restrict__ bias,
    const u16* __restrict__ addend, u16* __restrict__ out,
    int M, int O, int K, int NY)
{
    constexpr int NJ = BN / 32;
    constexpr int NB = (BN * 4) / 256;
    const int nyz = NY * 3;
    const int wg = xcd_map(blockIdx.x, gridDim.x);
    const int yz = wg % nyz;
    const int mb = wg / nyz;
    const int m0 = mb * 128;
    const int o0 = (yz % NY) * BN;
    const int st = yz / NY;
    const u16* Ak = A + (size_t)st * stOffA;
    const u16* Wk = Wt + (size_t)st * O * K;
    __shared__ u16 As[128][40];
    __shared__ u16 Bs[BN][40];
    const int tid = threadIdx.x;
    const int lane = tid & 63, wave = tid >> 6;
    const int wrow = wave >> 1, wcol = wave & 1;
    const int l15 = lane & 15, l4 = lane >> 4;
    f32x4 acc[4][NJ] = {};
    for (int kt = 0; kt < K; kt += 32) {
#pragma unroll
        for (int hh = 0; hh < 2; hh++) {
            int c = tid + hh * 256;
            int row = c >> 2, kc = (c & 3) * 8;
            int gr = m0 + row;
            uint4 v = {0, 0, 0, 0};
            if (gr < M) v = *(const uint4*)&Ak[(size_t)gr * pitchA + kt + kc];
            *(uint4*)&As[row][kc] = v;
        }
#pragma unroll
        for (int hh = 0; hh < NB; hh++) {
            int c = tid + hh * 256;
            int row = c >> 2, kc = (c & 3) * 8;
            *(uint4*)&Bs[row][kc] = *(const uint4*)&Wk[(size_t)(o0 + row) * K + kt + kc];
        }
        __syncthreads();
        s16x8 bfr[NJ];
#pragma unroll
        for (int j = 0; j < NJ; j++)
            bfr[j] = *(const s16x8*)&Bs[wcol * (BN / 2) + j * 16 + l15][l4 * 8];
#pragma unroll
        for (int i = 0; i < 4; i++) {
            s16x8 a = *(const s16x8*)&As[wrow * 64 + i * 16 + l15][l4 * 8];
#pragma unroll
            for (int j = 0; j < NJ; j++)
                acc[i][j] = __builtin_amdgcn_mfma_f32_16x16x32_bf16(bfr[j], a, acc[i][j], 0, 0, 0);
        }
        __syncthreads();
    }
#pragma unroll
    for (int i = 0; i < 4; i++) {
        int rg = m0 + wrow * 64 + i * 16 + l15;
        if (rg >= M) continue;
#pragma unroll
        for (int j = 0; j < NJ; j++) {
            int cgb = o0 + wcol * (BN / 2) + j * 16 + l4 * 4;
            size_t ob = ((size_t)rg * 3 + st) * O + cgb;
            float4 bv = {0.f, 0.f, 0.f, 0.f};
            if (HAS_BIAS) bv = *(const float4*)&bias[st * O + cgb];
            u64 av = 0;
            if (HAS_ADD) av = *(const u64*)&addend[ob];
            u16 o[4];
#pragma unroll
            for (int q = 0; q < 4; q++) {
                float v = acc[i][j][q];
                if (HAS_BIAS) v += (&bv.x)[q];
                if (HAS_ADD) v += bf2f((u16)(av >> (16 * q)));
                if (RELU) v = fmaxf(v, 0.0f);
                o[q] = f2bf(v);
            }
            *(u64*)&out[ob] = *(u64*)o;
        }
    }
}

// ---------------- fused dual GEMM (single k-loop) + XCD swizzle + 8B stores ----------
template<int RELU2>
__global__ __launch_bounds__(256) void gemm_dual(
    const u16* __restrict__ A1, const u16* __restrict__ A2,
    const u16* __restrict__ W1, const u16* __restrict__ W2,
    const float* __restrict__ bias,
    u16* __restrict__ out1, u16* __restrict__ out2,
    int M, int O, int K, int NY)
{
    const int nyz = NY * 3;
    const int wg = xcd_map(blockIdx.x, gridDim.x);
    const int yz = wg % nyz;
    const int mb = wg / nyz;
    const int m0 = mb * 128;
    const int o0 = (yz % NY) * 64;
    const int st = yz / NY;
    const u16* W1k = W1 + (size_t)st * O * K;
    const u16* W2k = W2 + (size_t)st * O * K;
    __shared__ u16 As1[128][40];
    __shared__ u16 As2[128][40];
    __shared__ u16 Bs1[64][40];
    __shared__ u16 Bs2[64][40];
    const int tid = threadIdx.x;
    const int lane = tid & 63, wave = tid >> 6;
    const int wrow = wave >> 1, wcol = wave & 1;
    const int l15 = lane & 15, l4 = lane >> 4;
    const int srow = tid >> 2;
    const int skoff = (tid & 3) * 8;

    f32x4 acc1[4][2] = {};
    f32x4 acc2[4][2] = {};
    for (int kt = 0; kt < K; kt += 32) {
#pragma unroll
        for (int hh = 0; hh < 2; hh++) {
            int c = tid + hh * 256;
            int row = c >> 2, kc = (c & 3) * 8;
            int gr = m0 + row;
            uint4 v1 = {0, 0, 0, 0}, v2 = {0, 0, 0, 0};
            if (gr < M) {
                v1 = *(const uint4*)&A1[(size_t)gr * K + kt + kc];
                v2 = *(const uint4*)&A2[(size_t)gr * K + kt + kc];
            }
            *(uint4*)&As1[row][kc] = v1;
            *(uint4*)&As2[row][kc] = v2;
        }
        *(uint4*)&Bs1[srow][skoff] = *(const uint4*)&W1k[(size_t)(o0 + srow) * K + kt + skoff];
        *(uint4*)&Bs2[srow][skoff] = *(const uint4*)&W2k[(size_t)(o0 + srow) * K + kt + skoff];
        __syncthreads();
        s16x8 b10 = *(const s16x8*)&Bs1[wcol * 32 + l15][l4 * 8];
        s16x8 b11 = *(const s16x8*)&Bs1[wcol * 32 + 16 + l15][l4 * 8];
        s16x8 b20 = *(const s16x8*)&Bs2[wcol * 32 + l15][l4 * 8];
        s16x8 b21 = *(const s16x8*)&Bs2[wcol * 32 + 16 + l15][l4 * 8];
#pragma unroll
        for (int i = 0; i < 4; i++) {
            s16x8 a1 = *(const s16x8*)&As1[wrow * 64 + i * 16 + l15][l4 * 8];
            s16x8 a2 = *(const s16x8*)&As2[wrow * 64 + i * 16 + l15][l4 * 8];
            acc1[i][0] = __builtin_amdgcn_mfma_f32_16x16x32_bf16(b10, a1, acc1[i][0], 0, 0, 0);
            acc1[i][1] = __builtin_amdgcn_mfma_f32_16x16x32_bf16(b11, a1, acc1[i][1], 0, 0, 0);
            acc2[i][0] = __builtin_amdgcn_mfma_f32_16x16x32_bf16(b20, a2, acc2[i][0], 0, 0, 0);
            acc2[i][1] = __builtin_amdgcn_mfma_f32_16x16x32_bf16(b21, a2, acc2[i][1], 0, 0, 0);
        }
        __syncthreads();
    }
#pragma unroll
    for (int i = 0; i < 4; i++) {
        int rg = m0 + wrow * 64 + i * 16 + l15;
        if (rg >= M) continue;
#pragma unroll
        for (int j = 0; j < 2; j++) {
            int cgb = o0 + wcol * 32 + j * 16 + l4 * 4;
            size_t ob = ((size_t)rg * 3 + st) * O + cgb;
            float4 bv = *(const float4*)&bias[st * O + cgb];
            u16 o1[4], o2[4];
#pragma unroll
            for (int q = 0; q < 4; q++) {
                float v1 = acc1[i][j][q] + (&bv.x)[q];
                o1[q] = f2bf(v1);
                float v2 = acc2[i][j][q] + v1;
                if (RELU2) v2 = fmaxf(v2, 0.0f);
                o2[q] = f2bf(v2);
            }
            *(u64*)&out1[ob] = *(u64*)o1;
            *(u64*)&out2[ob] = *(u64*)o2;
        }
    }
}

// ---------------- mean over 3 stacks, F=256: [N][3][256] -> [N][256] ----------------
__global__ void mean3_256(const u16* __restrict__ h, u16* __restrict__ out) {
    long idx = (long)blockIdx.x * blockDim.x + threadIdx.x;  // u32 index
    const long total = (long)NN * 128;
    if (idx >= total) return;
    long n = idx >> 7; int t = (int)(idx & 127);
    const u32* hu = (const u32*)h;
    u32 a = hu[(n * 3 + 0) * 128 + t], b = hu[(n * 3 + 1) * 128 + t], c = hu[(n * 3 + 2) * 128 + t];
    float lo = (bf2f((u16)a) + bf2f((u16)b) + bf2f((u16)c)) * (1.0f / 3.0f);
    float hi = (bf2f((u16)(a >> 16)) + bf2f((u16)(b >> 16)) + bf2f((u16)(c >> 16))) * (1.0f / 3.0f);
    ((u32*)out)[idx] = (u32)f2bf(lo) | ((u32)f2bf(hi) << 16);
}

// ---------------- mean over stacks + log_softmax, g [N][3][64] -> out [N][64] f32 -----
__global__ __launch_bounds__(64) void final_ls(const u16* __restrict__ g, float* __restrict__ out) {
    int n = blockIdx.x;
    int f = threadIdx.x;
    long b0 = (long)n * 192 + f;
    float v = (bf2f(g[b0]) + bf2f(g[b0 + 64]) + bf2f(g[b0 + 128])) * (1.0f / 3.0f);
    float m = v;
    for (int off = 32; off; off >>= 1) m = fmaxf(m, __shfl_xor(m, off, 64));
    float s = expf(v - m);
    for (int off = 32; off; off >>= 1) s += __shfl_xor(s, off, 64);
    out[(long)n * 64 + f] = v - m - logf(s);
}

extern "C" void kernel_launch(void* const* d_in, const int* in_sizes, int n_in,
                              void* d_out, int out_size, void* d_ws, size_t ws_size,
                              hipStream_t stream) {
    const float* x = (const float*)d_in[0];
    const int* ei = (const int*)d_in[1];
    const float* init_w1 = (const float*)d_in[2];
    const float* w1 = (const float*)d_in[3];
    const float* root_w1 = (const float*)d_in[4];
    const float* bias1 = (const float*)d_in[5];
    const float* init_w2 = (const float*)d_in[6];
    const float* w2 = (const float*)d_in[7];
    const float* root_w2 = (const float*)d_in[8];
    const float* bias2 = (const float*)d_in[9];
    float* out = (float*)d_out;
    (void)ws_size; (void)n_in; (void)in_sizes; (void)out_size;

    char* ws = (char*)d_ws;
    size_t off = 0;
    auto alloc = [&](size_t bytes) -> void* {
        void* p = ws + off;
        off += (bytes + 255) & ~(size_t)255;
        return p;
    };
    int* deg = (int*)alloc(NN * 4);
    int* rowptr = (int*)alloc((NN + 1) * 4);
    int* cursor = (int*)alloc(NN * 4);
    int* srcb = (int*)alloc((size_t)NE * 4);
    float* ewb = (float*)alloc((size_t)NE * 4);
    float* dis = (float*)alloc(NN * 4);
    u16* iw1t = (u16*)alloc((size_t)3 * 256 * 256 * 2);
    u16* w1t = (u16*)alloc((size_t)3 * 256 * 256 * 2);
    u16* rw1t = (u16*)alloc((size_t)3 * 256 * 256 * 2);
    u16* iw2t = (u16*)alloc((size_t)3 * 64 * 256 * 2);
    u16* rw2t = (u16*)alloc((size_t)3 * 64 * 256 * 2);
    u16* w2t = (u16*)alloc((size_t)3 * 64 * 64 * 2);
    u16* xb = (u16*)alloc((size_t)NN * 256 * 2);            // x bf16 [N][256]
    u16* bufR = (u16*)alloc((size_t)NN * 3 * 256 * 2);      // root1; then conv2 quads
    u16* bufH = (u16*)alloc((size_t)NN * 3 * 256 * 2);      // h1, then h2
    u16* bufP = (u16*)alloc((size_t)NN * 3 * 256 * 2);      // px | ph1 | hmean
    u16* px = bufP;            // [N][256] (dead before ph1 written)
    u16* hmean = bufP;         // [N][256] (after ph1 dead)
    u16* pm = xb;              // [N][256] (xb dead after dual1)
    // conv2 carves from bufR (root1 dead after h2 GEMM): 4 x 11.52 MB
    u16* root2 = bufR;
    u16* g1 = bufR + (size_t)3 * NN * 64;
    u16* pg1 = bufR + (size_t)6 * NN * 64;
    u16* g2 = bufR + (size_t)9 * NN * 64;

    const int* e_row = ei;
    const int* e_col = ei + NE;

    hipMemsetAsync(deg, 0, NN * 4, stream);
    hipMemsetAsync(cursor, 0, NN * 4, stream);

    hist_kernel<<<(NE + 255) / 256, 256, 0, stream>>>(e_col, deg);
    dis_kernel<<<(NN + 255) / 256, 256, 0, stream>>>(deg, dis);
    scan_kernel<<<1, 1024, 0, stream>>>(deg, rowptr);
    scatter_kernel<<<(NE + 255) / 256, 256, 0, stream>>>(e_row, e_col, rowptr, cursor, dis, srcb, ewb);

    f2bf_vec<<<(NN * 256 / 4 + 255) / 256, 256, 0, stream>>>(x, xb, (long)NN * 256 / 4);
    prep_w<<<(3 * 256 * 256 + 255) / 256, 256, 0, stream>>>(init_w1, iw1t, 256, 256);
    prep_w<<<(3 * 256 * 256 + 255) / 256, 256, 0, stream>>>(w1, w1t, 256, 256);
    prep_w<<<(3 * 256 * 256 + 255) / 256, 256, 0, stream>>>(root_w1, rw1t, 256, 256);
    prep_w<<<(3 * 64 * 256 + 255) / 256, 256, 0, stream>>>(init_w2, iw2t, 256, 64);
    prep_w<<<(3 * 64 * 256 + 255) / 256, 256, 0, stream>>>(root_w2, rw2t, 256, 64);
    prep_w<<<(3 * 64 * 64 + 255) / 256, 256, 0, stream>>>(w2, w2t, 64, 64);

    const int MB = (NN + 127) / 128;  // 235

    // ---- conv1 ----
    // px = prop(x)
    prop_node<64><<<NN, 64, 0, stream>>>(xb, px, rowptr, srcb, ewb);
    // root1 = x@rw1+b1 ; h1 = relu(px@iw1 + root1)   [N][3][256]
    gemm_dual<1><<<MB * 12, 256, 0, stream>>>(xb, px, rw1t, iw1t, bias1,
                                              bufR, bufH, NN, 256, 256, 4);
    // ph1 = prop(h1)  (3-stack, [N][768])
    prop_node<192><<<NN, 192, 0, stream>>>(bufH, bufP, rowptr, srcb, ewb);
    // h2 = relu(ph1@w1 + root1)
    gemm_one<128, 1, 0, 1><<<MB * 6, 256, 0, stream>>>(
        bufP, 768, 256, w1t, nullptr, bufR, bufH, NN, 256, 256, 2);
    // hmean = mean_stacks(h2)   (>=0, so outer relu is a no-op)
    mean3_256<<<(int)(((long)NN * 128 + 255) / 256), 256, 0, stream>>>(bufH, hmean);

    // ---- conv2 ----
    // pm = prop(hmean)
    prop_node<64><<<NN, 64, 0, stream>>>(hmean, pm, rowptr, srcb, ewb);
    // root2 = hmean@rw2+b2 ; g1 = pm@iw2 + root2   [N][3][64]
    gemm_dual<0><<<MB * 3, 256, 0, stream>>>(hmean, pm, rw2t, iw2t, bias2,
                                             root2, g1, NN, 64, 256, 1);
    // pg1 = prop(g1)  (3-stack, [N][192])
    prop_node<48><<<NN, 64, 0, stream>>>(g1, pg1, rowptr, srcb, ewb);
    // g2 = pg1@w2 + root2
    gemm_one<64, 1, 0, 0><<<MB * 3, 256, 0, stream>>>(
        pg1, 192, 64, w2t, nullptr, root2, g2, NN, 64, 64, 1);

    final_ls<<<NN, 64, 0, stream>>>(g2, out);
}